// Round 13
// baseline (184.390 us; speedup 1.0000x reference)
//
#include <hip/hip_runtime.h>
#include <cstdint>

typedef unsigned short u16;
typedef short s16x8 __attribute__((ext_vector_type(8)));
typedef short s16x4 __attribute__((ext_vector_type(4)));
typedef float f32x4 __attribute__((ext_vector_type(4)));
typedef float f32x16 __attribute__((ext_vector_type(16)));

#define B_   4
#define T_   2048
#define C_   1024
#define H_   16
#define HD_  64
#define M_   8192      // B*T
#define N3_  3072      // 3*C

// 0.125 (1/sqrt(64)) * log2(e), folded into q at QKV-GEMM epilogue
#define QSCALE 0.18033688011112042f

// fp32 -> bf16 round-to-nearest-even
__device__ inline u16 f2b(float f) {
  union { float f; uint32_t u; } v; v.f = f;
  uint32_t u = v.u;
  return (u16)((u + 0x7FFFu + ((u >> 16) & 1u)) >> 16);
}

// pack 2 fp32 -> 2 bf16 in one dword (RNE): dst.lo = src0, dst.hi = src1
__device__ inline uint32_t cvtpk(float lo, float hi) {
  uint32_t r;
  asm("v_cvt_pk_bf16_f32 %0, %1, %2" : "=v"(r) : "v"(lo), "v"(hi));
  return r;
}

// async global->LDS, 16B per lane (dest = wave-uniform base + lane*16)
__device__ inline void gload_lds16(const void* g, void* l) {
  __builtin_amdgcn_global_load_lds(
      (const __attribute__((address_space(1))) void*)g,
      (__attribute__((address_space(3))) void*)l, 16, 0, 0);
}

// ---------------- convert x (fp32) -> bf16, same layout ----------------
__global__ __launch_bounds__(256) void cvt_f32_bf16(
    const float* __restrict__ in, u16* __restrict__ out, int n) {
  int i = (blockIdx.x * 256 + threadIdx.x) * 8;
  if (i >= n) return;
  float4 a = *(const float4*)(in + i);
  float4 b = *(const float4*)(in + i + 4);
  s16x8 r;
  r[0] = (short)f2b(a.x); r[1] = (short)f2b(a.y);
  r[2] = (short)f2b(a.z); r[3] = (short)f2b(a.w);
  r[4] = (short)f2b(b.x); r[5] = (short)f2b(b.y);
  r[6] = (short)f2b(b.z); r[7] = (short)f2b(b.w);
  *(s16x8*)(out + i) = r;
}

// ------- transpose+convert: W fp32 [K][N] -> WT bf16 [N][K] ------------
__global__ __launch_bounds__(256) void cvt_transpose(
    const float* __restrict__ W, u16* __restrict__ WT, int K, int N) {
  __shared__ u16 tile[64][65];
  int n0 = blockIdx.x * 64, k0 = blockIdx.y * 64;
  int j = threadIdx.x & 63, i0 = threadIdx.x >> 6;  // j fast, i0 in 0..3
#pragma unroll
  for (int i = i0; i < 64; i += 4)
    tile[i][j] = f2b(W[(size_t)(k0 + i) * N + n0 + j]);
  __syncthreads();
#pragma unroll
  for (int i = i0; i < 64; i += 4)
    WT[(size_t)(n0 + i) * K + k0 + j] = tile[j][i];
}

// ---------------- GEMM: C[M][N] = A[M][K] * Bt[N][K]^T + bias ----------
// 2-barrier structure (measured-best, r10), BK=64, 128x128 tile, 4 waves,
// 32 KB LDS. Chunk-XOR swizzle via pre-swizzled global source -> 0 conflicts.
// MODE 0: fp32 out.  MODE 1: scatter bf16 q,k->[B,H,T,64] (q pre-scaled),
//                            v -> transposed [B,H,64,T].
template <int MODE>
__global__ __launch_bounds__(256, 4) void gemm_bt(
    const u16* __restrict__ A, const u16* __restrict__ Bt,
    const float* __restrict__ bias, float* __restrict__ outf,
    u16* __restrict__ qo, u16* __restrict__ ko, u16* __restrict__ vo,
    int M, int N, int K) {
  __shared__ u16 As[128 * 64];   // 16 KB, rows 128B, chunk-swizzled
  __shared__ u16 Bs[128 * 64];   // 16 KB

  int nwg = gridDim.x;
  int bid0 = blockIdx.x;
  int bid = (bid0 & 7) * (nwg >> 3) + (bid0 >> 3);   // XCD swizzle (nwg%8==0)
  int nbn = N >> 7;
  int bm = bid / nbn, bn = bid % nbn;
  int m0 = bm * 128, n0 = bn * 128;
  int tid = threadIdx.x;
  int lane = tid & 63, w = tid >> 6;
  int wm = (w >> 1) * 64, wn = (w & 1) * 64;
  int l15 = lane & 15, g = lane >> 4;

  f32x4 acc[4][4] = {};

  for (int kb = 0; kb < K; kb += 64) {
    __syncthreads();  // all waves done reading previous tile
#pragma unroll
    for (int p = 0; p < 4; ++p) {
      int idx = p * 256 + tid;
      int row = idx >> 3, pc = idx & 7;
      int sc = (pc ^ (row & 7)) * 8;     // pre-swizzled source chunk
      gload_lds16(A  + (size_t)(m0 + row) * K + kb + sc, &As[idx * 8]);
      gload_lds16(Bt + (size_t)(n0 + row) * K + kb + sc, &Bs[idx * 8]);
    }
    __syncthreads();  // (compiler emits vmcnt(0) before barrier)

#pragma unroll
    for (int ks = 0; ks < 2; ++ks) {
      int ck = ((g + 4 * ks) ^ (l15 & 7)) * 8;   // swizzled read chunk
      s16x8 af[4], bf[4];
#pragma unroll
      for (int mi = 0; mi < 4; ++mi)
        af[mi] = *(const s16x8*)&As[(wm + mi * 16 + l15) * 64 + ck];
#pragma unroll
      for (int ni = 0; ni < 4; ++ni)
        bf[ni] = *(const s16x8*)&Bs[(wn + ni * 16 + l15) * 64 + ck];
#pragma unroll
      for (int mi = 0; mi < 4; ++mi)
#pragma unroll
        for (int ni = 0; ni < 4; ++ni)
          acc[mi][ni] = __builtin_amdgcn_mfma_f32_16x16x32_bf16(
              af[mi], bf[ni], acc[mi][ni], 0, 0, 0);
    }
  }

#pragma unroll
  for (int mi = 0; mi < 4; ++mi)
#pragma unroll
    for (int ni = 0; ni < 4; ++ni) {
      int col = n0 + wn + ni * 16 + l15;
      float bv = bias[col];
      int row0 = m0 + wm + mi * 16 + g * 4;  // C/D: col=lane&15, row=(lane>>4)*4+reg
      if (MODE == 0) {
#pragma unroll
        for (int r = 0; r < 4; ++r)
          outf[(size_t)(row0 + r) * N + col] = acc[mi][ni][r] + bv;
      } else {
        int which = col >> 10, hc = col & 1023;
        int h = hc >> 6, d = hc & 63;
        int b = row0 >> 11, t0 = row0 & 2047;
        if (which == 2) {
          s16x4 pv;
#pragma unroll
          for (int r = 0; r < 4; ++r) pv[r] = (short)f2b(acc[mi][ni][r] + bv);
          *(s16x4*)(vo + ((size_t)((b * 16 + h) * 64 + d)) * 2048 + t0) = pv;
        } else {
          u16* dst = (which == 0) ? qo : ko;
          float sc2 = (which == 0) ? QSCALE : 1.0f;
#pragma unroll
          for (int r = 0; r < 4; ++r)
            dst[(((size_t)(b * 16 + h)) * 2048 + (t0 + r)) * 64 + d] =
                f2b((acc[mi][ni][r] + bv) * sc2);
        }
      }
    }
}

// ---------------- flash attention, causal, 32x32 MFMA, swapped QK^T ----
// grid: 64 (b,h) x 8 q-tiles of 256 rows; block 256 = 4 waves x 64 q-rows.
// Each wave owns TWO 32-row q-subtiles (A: qw..qw+31, B: qw+32..qw+63):
// every K-fragment and V-fragment ds_read feeds TWO MFMAs -> per-q LDS
// traffic halves vs r10 (the DS-bound lever). S^T = mfma32(K, Q); P stays
// in-register (cvt_pk + send-select shfl_xor(32)).
__global__ __launch_bounds__(256, 2) void attn_fwd(
    const u16* __restrict__ Q, const u16* __restrict__ Kg,
    const u16* __restrict__ Vt, u16* __restrict__ Y) {
  __shared__ u16 Ks[64 * 64];   // K tile  [kv][hd], 128B rows, swizzled
  __shared__ u16 Vs[64 * 64];   // V^T tile [hd][kv], 128B rows, swizzled

  int bid = blockIdx.x;
  int bh = bid & 63;
  int qb = 7 - (bid >> 6);        // big tiles first
  int tid = threadIdx.x, lane = tid & 63, w = tid >> 6;
  int l31 = lane & 31, half = lane >> 5;

  const u16* Qh = Q  + (size_t)bh * T_ * HD_;
  const u16* Kh = Kg + (size_t)bh * T_ * HD_;
  const u16* Vh = Vt + (size_t)bh * HD_ * T_;   // [64][2048]

  int q0 = qb * 256;
  int qw = q0 + w * 64;           // wave's first q row (multiple of 64)
  int qrA = qw + l31;             // qsub A row
  int qrB = qw + 32 + l31;        // qsub B row

  // Q in registers: 4 k-steps x 16B (k = kst*16 + half*8 + e), per qsub
  s16x8 qaA[4], qaB[4];
#pragma unroll
  for (int kst = 0; kst < 4; ++kst) {
    qaA[kst] = *(const s16x8*)(Qh + (size_t)qrA * HD_ + kst * 16 + half * 8);
    qaB[kst] = *(const s16x8*)(Qh + (size_t)qrB * HD_ + kst * 16 + half * 8);
  }

  f32x16 oA0 = {}, oA1 = {}, oB0 = {}, oB1 = {};  // O^T per qsub, hd-blocks 0/1
  float mA = -3.0e30f, lA = 0.f, mB = -3.0e30f, lB = 0.f;

  int sr = tid >> 3, sc = tid & 7;
  int wswz = (sr & 7) << 4;
  int rswz = (l31 & 7) << 4;
  char* KsB = (char*)Ks;
  char* VsB = (char*)Vs;

  s16x8 kr0 = *(const s16x8*)(Kh + (size_t)sr * HD_ + sc * 8);
  s16x8 kr1 = *(const s16x8*)(Kh + (size_t)(sr + 32) * HD_ + sc * 8);
  s16x8 vr0 = *(const s16x8*)(Vh + (size_t)sr * T_ + sc * 8);
  s16x8 vr1 = *(const s16x8*)(Vh + (size_t)(sr + 32) * T_ + sc * 8);

  int ntile = 4 * qb + 4;
  for (int kt = 0; kt < ntile; ++kt) {
    int kvb = kt * 64;
    __syncthreads();              // previous tile's reads done
    *(s16x8*)(KsB + sr * 128 + ((sc * 16) ^ wswz))        = kr0;
    *(s16x8*)(KsB + (sr + 32) * 128 + ((sc * 16) ^ wswz)) = kr1;
    *(s16x8*)(VsB + sr * 128 + ((sc * 16) ^ wswz))        = vr0;
    *(s16x8*)(VsB + (sr + 32) * 128 + ((sc * 16) ^ wswz)) = vr1;
    __syncthreads();              // tile visible

    // T14: issue NEXT tile's global loads now; latency hides under compute
    {
      int kvn = (kt + 1 < ntile) ? (kt + 1) * 64 : 0;
      kr0 = *(const s16x8*)(Kh + (size_t)(kvn + sr) * HD_ + sc * 8);
      kr1 = *(const s16x8*)(Kh + (size_t)(kvn + sr + 32) * HD_ + sc * 8);
      vr0 = *(const s16x8*)(Vh + (size_t)sr * T_ + kvn + sc * 8);
      vr1 = *(const s16x8*)(Vh + (size_t)(sr + 32) * T_ + kvn + sc * 8);
    }

    // wave-level skip of fully-masked tiles (barriers stay block-uniform)
    if (kvb > qw + 63) continue;

    // S^T = K Q^T: each K fragment read feeds BOTH qsubs
    f32x16 sA0 = {}, sA1 = {}, sB0 = {}, sB1 = {};
    __builtin_amdgcn_s_setprio(1);
#pragma unroll
    for (int kst = 0; kst < 4; ++kst) {
      s16x8 kb0 = *(const s16x8*)(KsB +
          ((l31 * 128 + kst * 32 + half * 16) ^ rswz));
      sA0 = __builtin_amdgcn_mfma_f32_32x32x16_bf16(kb0, qaA[kst], sA0, 0, 0, 0);
      sB0 = __builtin_amdgcn_mfma_f32_32x32x16_bf16(kb0, qaB[kst], sB0, 0, 0, 0);
      s16x8 kb1 = *(const s16x8*)(KsB +
          (((32 + l31) * 128 + kst * 32 + half * 16) ^ rswz));
      sA1 = __builtin_amdgcn_mfma_f32_32x32x16_bf16(kb1, qaA[kst], sA1, 0, 0, 0);
      sB1 = __builtin_amdgcn_mfma_f32_32x32x16_bf16(kb1, qaB[kst], sB1, 0, 0, 0);
    }
    __builtin_amdgcn_s_setprio(0);

    // causal mask (tiles that cross any diagonal in this wave's 64 rows)
    if (kvb + 63 > qw) {
#pragma unroll
      for (int r = 0; r < 16; ++r) {
        int kv0 = kvb + (r & 3) + 8 * (r >> 2) + 4 * half;
        if (kv0 > qrA)      sA0[r] = -1e30f;
        if (kv0 + 32 > qrA) sA1[r] = -1e30f;
        if (kv0 > qrB)      sB0[r] = -1e30f;
        if (kv0 + 32 > qrB) sB1[r] = -1e30f;
      }
    }

    // row max per qsub: in-lane tree + one ^32 combine (lane^32 = same q)
    float mxA, mxB;
    {
      float a0 = fmaxf(fmaxf(sA0[0], sA0[1]), fmaxf(sA0[2], sA0[3]));
      float a1 = fmaxf(fmaxf(sA0[4], sA0[5]), fmaxf(sA0[6], sA0[7]));
      float a2 = fmaxf(fmaxf(sA0[8], sA0[9]), fmaxf(sA0[10], sA0[11]));
      float a3 = fmaxf(fmaxf(sA0[12], sA0[13]), fmaxf(sA0[14], sA0[15]));
      float a4 = fmaxf(fmaxf(sA1[0], sA1[1]), fmaxf(sA1[2], sA1[3]));
      float a5 = fmaxf(fmaxf(sA1[4], sA1[5]), fmaxf(sA1[6], sA1[7]));
      float a6 = fmaxf(fmaxf(sA1[8], sA1[9]), fmaxf(sA1[10], sA1[11]));
      float a7 = fmaxf(fmaxf(sA1[12], sA1[13]), fmaxf(sA1[14], sA1[15]));
      mxA = fmaxf(fmaxf(fmaxf(a0, a1), fmaxf(a2, a3)),
                  fmaxf(fmaxf(a4, a5), fmaxf(a6, a7)));
      mxA = fmaxf(mxA, __shfl_xor(mxA, 32, 64));
      float b0 = fmaxf(fmaxf(sB0[0], sB0[1]), fmaxf(sB0[2], sB0[3]));
      float b1 = fmaxf(fmaxf(sB0[4], sB0[5]), fmaxf(sB0[6], sB0[7]));
      float b2 = fmaxf(fmaxf(sB0[8], sB0[9]), fmaxf(sB0[10], sB0[11]));
      float b3 = fmaxf(fmaxf(sB0[12], sB0[13]), fmaxf(sB0[14], sB0[15]));
      float b4 = fmaxf(fmaxf(sB1[0], sB1[1]), fmaxf(sB1[2], sB1[3]));
      float b5 = fmaxf(fmaxf(sB1[4], sB1[5]), fmaxf(sB1[6], sB1[7]));
      float b6 = fmaxf(fmaxf(sB1[8], sB1[9]), fmaxf(sB1[10], sB1[11]));
      float b7 = fmaxf(fmaxf(sB1[12], sB1[13]), fmaxf(sB1[14], sB1[15]));
      mxB = fmaxf(fmaxf(fmaxf(b0, b1), fmaxf(b2, b3)),
                  fmaxf(fmaxf(b4, b5), fmaxf(b6, b7)));
      mxB = fmaxf(mxB, __shfl_xor(mxB, 32, 64));
    }

    // T13 defer-max (combined branch for both qsubs)
    if (!__all(mxA <= mA + 8.0f && mxB <= mB + 8.0f)) {
      float mnA = fmaxf(mA, mxA), mnB = fmaxf(mB, mxB);
      float aA = __builtin_amdgcn_exp2f(mA - mnA);
      float aB = __builtin_amdgcn_exp2f(mB - mnB);
      mA = mnA; mB = mnB;
      lA *= aA; lB *= aB;
#pragma unroll
      for (int i = 0; i < 16; ++i) {
        oA0[i] *= aA; oA1[i] *= aA;
        oB0[i] *= aB; oB1[i] *= aB;
      }
    }

    float rsA = 0.f, rsB = 0.f;
#pragma unroll
    for (int r = 0; r < 16; ++r) {
      float pa0 = __builtin_amdgcn_exp2f(sA0[r] - mA);
      float pa1 = __builtin_amdgcn_exp2f(sA1[r] - mA);
      float pb0 = __builtin_amdgcn_exp2f(sB0[r] - mB);
      float pb1 = __builtin_amdgcn_exp2f(sB1[r] - mB);
      sA0[r] = pa0; sA1[r] = pa1; sB0[r] = pb0; sB1[r] = pb1;
      rsA += pa0 + pa1; rsB += pb0 + pb1;
    }
    rsA += __shfl_xor(rsA, 32, 64);
    rsB += __shfl_xor(rsB, 32, 64);
    lA += rsA; lB += rsB;

    // P^T B-fragments per qsub (send-select, verified r10)
    s16x8 pbA[4], pbB[4];
#pragma unroll
    for (int ks4 = 0; ks4 < 4; ++ks4) {
      const f32x16& svA = (ks4 < 2) ? sA0 : sA1;
      const f32x16& svB = (ks4 < 2) ? sB0 : sB1;
      const int R = (ks4 & 1) * 8;
      uint32_t Aa0 = cvtpk(svA[R + 0], svA[R + 1]);
      uint32_t Aa1 = cvtpk(svA[R + 2], svA[R + 3]);
      uint32_t Ab0 = cvtpk(svA[R + 4], svA[R + 5]);
      uint32_t Ab1 = cvtpk(svA[R + 6], svA[R + 7]);
      uint32_t ra0 = (uint32_t)__shfl_xor((int)(half ? Aa0 : Ab0), 32, 64);
      uint32_t ra1 = (uint32_t)__shfl_xor((int)(half ? Aa1 : Ab1), 32, 64);
      union { uint32_t u[4]; s16x8 v; } pkA;
      pkA.u[0] = half ? ra0 : Aa0;
      pkA.u[1] = half ? ra1 : Aa1;
      pkA.u[2] = half ? Ab0 : ra0;
      pkA.u[3] = half ? Ab1 : ra1;
      pbA[ks4] = pkA.v;
      uint32_t Ba0 = cvtpk(svB[R + 0], svB[R + 1]);
      uint32_t Ba1 = cvtpk(svB[R + 2], svB[R + 3]);
      uint32_t Bb0 = cvtpk(svB[R + 4], svB[R + 5]);
      uint32_t Bb1 = cvtpk(svB[R + 6], svB[R + 7]);
      uint32_t rb0 = (uint32_t)__shfl_xor((int)(half ? Ba0 : Bb0), 32, 64);
      uint32_t rb1 = (uint32_t)__shfl_xor((int)(half ? Ba1 : Bb1), 32, 64);
      union { uint32_t u[4]; s16x8 v; } pkB;
      pkB.u[0] = half ? rb0 : Ba0;
      pkB.u[1] = half ? rb1 : Ba1;
      pkB.u[2] = half ? Bb0 : rb0;
      pkB.u[3] = half ? Bb1 : rb1;
      pbB[ks4] = pkB.v;
    }

    // O^T += V^T P^T: each V fragment read feeds BOTH qsubs
    __builtin_amdgcn_s_setprio(1);
#pragma unroll
    for (int ks4 = 0; ks4 < 4; ++ks4) {
      s16x8 va0 = *(const s16x8*)(VsB +
          ((l31 * 128 + ks4 * 32 + half * 16) ^ rswz));
      oA0 = __builtin_amdgcn_mfma_f32_32x32x16_bf16(va0, pbA[ks4], oA0, 0, 0, 0);
      oB0 = __builtin_amdgcn_mfma_f32_32x32x16_bf16(va0, pbB[ks4], oB0, 0, 0, 0);
      s16x8 va1 = *(const s16x8*)(VsB +
          (((32 + l31) * 128 + ks4 * 32 + half * 16) ^ rswz));
      oA1 = __builtin_amdgcn_mfma_f32_32x32x16_bf16(va1, pbA[ks4], oA1, 0, 0, 0);
      oB1 = __builtin_amdgcn_mfma_f32_32x32x16_bf16(va1, pbB[ks4], oB1, 0, 0, 0);
    }
    __builtin_amdgcn_s_setprio(0);
  }

  // epilogue: Y[b][q][h*64 + hd], hd = hb*32 + rg*8 + half*4 + i
  int b = bh >> 4, h = bh & 15;
  float invA = 1.0f / lA, invB = 1.0f / lB;
  u16* yrA = Y + ((size_t)b * T_ + qrA) * C_ + h * 64;
  u16* yrB = Y + ((size_t)b * T_ + qrB) * C_ + h * 64;
#pragma unroll
  for (int rg = 0; rg < 4; ++rg) {
    union { uint32_t u[2]; s16x4 v; } o;
    o.u[0] = cvtpk(oA0[rg * 4 + 0] * invA, oA0[rg * 4 + 1] * invA);
    o.u[1] = cvtpk(oA0[rg * 4 + 2] * invA, oA0[rg * 4 + 3] * invA);
    *(s16x4*)(yrA + rg * 8 + half * 4) = o.v;
    o.u[0] = cvtpk(oA1[rg * 4 + 0] * invA, oA1[rg * 4 + 1] * invA);
    o.u[1] = cvtpk(oA1[rg * 4 + 2] * invA, oA1[rg * 4 + 3] * invA);
    *(s16x4*)(yrA + 32 + rg * 8 + half * 4) = o.v;
    o.u[0] = cvtpk(oB0[rg * 4 + 0] * invB, oB0[rg * 4 + 1] * invB);
    o.u[1] = cvtpk(oB0[rg * 4 + 2] * invB, oB0[rg * 4 + 3] * invB);
    *(s16x4*)(yrB + rg * 8 + half * 4) = o.v;
    o.u[0] = cvtpk(oB1[rg * 4 + 0] * invB, oB1[rg * 4 + 1] * invB);
    o.u[1] = cvtpk(oB1[rg * 4 + 2] * invB, oB1[rg * 4 + 3] * invB);
    *(s16x4*)(yrB + 32 + rg * 8 + half * 4) = o.v;
  }
}

// ----------------------------- launcher --------------------------------
extern "C" void kernel_launch(void* const* d_in, const int* in_sizes, int n_in,
                              void* d_out, int out_size, void* d_ws, size_t ws_size,
                              hipStream_t stream) {
  const float* x      = (const float*)d_in[0];
  const float* w_attn = (const float*)d_in[1];
  const float* b_attn = (const float*)d_in[2];
  const float* w_proj = (const float*)d_in[3];
  const float* b_proj = (const float*)d_in[4];
  float* out = (float*)d_out;

  u16* ws  = (u16*)d_ws;
  u16* xb  = ws;                           // [8192][1024] bf16 (reused as ya)
  u16* wat = xb  + (size_t)M_ * C_;        // [3072][1024] bf16 (W_attn^T)
  u16* wpt = wat + (size_t)N3_ * C_;       // [1024][1024] bf16 (W_proj^T)
  u16* q   = wpt + (size_t)C_ * C_;        // [B,H,T,64] bf16 (pre-scaled)
  u16* k   = q   + (size_t)M_ * C_;        // [B,H,T,64] bf16
  u16* v   = k   + (size_t)M_ * C_;        // [B,H,64,T] bf16 (TRANSPOSED)
  u16* ya  = xb;                           // reuse: xb dead after QKV GEMM

  cvt_f32_bf16<<<dim3((M_ * C_) / (256 * 8)), dim3(256), 0, stream>>>(x, xb, M_ * C_);
  cvt_transpose<<<dim3(N3_ / 64, C_ / 64), dim3(256), 0, stream>>>(w_attn, wat, C_, N3_);
  cvt_transpose<<<dim3(C_ / 64, C_ / 64), dim3(256), 0, stream>>>(w_proj, wpt, C_, C_);

  gemm_bt<1><<<dim3((M_ / 128) * (N3_ / 128)), dim3(256), 0, stream>>>(
      xb, wat, b_attn, nullptr, q, k, v, M_, N3_, C_);

  attn_fwd<<<dim3(64 * 8), dim3(256), 0, stream>>>(q, k, v, ya);

  gemm_bt<0><<<dim3((M_ / 128) * (C_ / 128)), dim3(256), 0, stream>>>(
      ya, wpt, b_proj, out, nullptr, nullptr, nullptr, M_, C_, C_);
}

// Round 14
// 174.196 us; speedup vs baseline: 1.0585x; 1.0585x over previous
//
#include <hip/hip_runtime.h>
#include <cstdint>

typedef unsigned short u16;
typedef short s16x8 __attribute__((ext_vector_type(8)));
typedef short s16x4 __attribute__((ext_vector_type(4)));
typedef float f32x4 __attribute__((ext_vector_type(4)));
typedef float f32x16 __attribute__((ext_vector_type(16)));

#define B_   4
#define T_   2048
#define C_   1024
#define H_   16
#define HD_  64
#define M_   8192      // B*T
#define N3_  3072      // 3*C

// 0.125 (1/sqrt(64)) * log2(e), folded into q at QKV-GEMM epilogue
#define QSCALE 0.18033688011112042f

// fp32 -> bf16 round-to-nearest-even
__device__ inline u16 f2b(float f) {
  union { float f; uint32_t u; } v; v.f = f;
  uint32_t u = v.u;
  return (u16)((u + 0x7FFFu + ((u >> 16) & 1u)) >> 16);
}

// pack 2 fp32 -> 2 bf16 in one dword (RNE): dst.lo = src0, dst.hi = src1
__device__ inline uint32_t cvtpk(float lo, float hi) {
  uint32_t r;
  asm("v_cvt_pk_bf16_f32 %0, %1, %2" : "=v"(r) : "v"(lo), "v"(hi));
  return r;
}

// async global->LDS, 16B per lane (dest = wave-uniform base + lane*16)
__device__ inline void gload_lds16(const void* g, void* l) {
  __builtin_amdgcn_global_load_lds(
      (const __attribute__((address_space(1))) void*)g,
      (__attribute__((address_space(3))) void*)l, 16, 0, 0);
}

// ---------------- convert x (fp32) -> bf16, same layout ----------------
__global__ __launch_bounds__(256) void cvt_f32_bf16(
    const float* __restrict__ in, u16* __restrict__ out, int n) {
  int i = (blockIdx.x * 256 + threadIdx.x) * 8;
  if (i >= n) return;
  float4 a = *(const float4*)(in + i);
  float4 b = *(const float4*)(in + i + 4);
  s16x8 r;
  r[0] = (short)f2b(a.x); r[1] = (short)f2b(a.y);
  r[2] = (short)f2b(a.z); r[3] = (short)f2b(a.w);
  r[4] = (short)f2b(b.x); r[5] = (short)f2b(b.y);
  r[6] = (short)f2b(b.z); r[7] = (short)f2b(b.w);
  *(s16x8*)(out + i) = r;
}

// ------- transpose+convert: W fp32 [K][N] -> WT bf16 [N][K] ------------
__global__ __launch_bounds__(256) void cvt_transpose(
    const float* __restrict__ W, u16* __restrict__ WT, int K, int N) {
  __shared__ u16 tile[64][65];
  int n0 = blockIdx.x * 64, k0 = blockIdx.y * 64;
  int j = threadIdx.x & 63, i0 = threadIdx.x >> 6;  // j fast, i0 in 0..3
#pragma unroll
  for (int i = i0; i < 64; i += 4)
    tile[i][j] = f2b(W[(size_t)(k0 + i) * N + n0 + j]);
  __syncthreads();
#pragma unroll
  for (int i = i0; i < 64; i += 4)
    WT[(size_t)(n0 + i) * K + k0 + j] = tile[j][i];
}

// ---------------- GEMM: C[M][N] = A[M][K] * Bt[N][K]^T + bias ----------
// 2-barrier structure (measured-best, r10), BK=64, 128x128 tile, 4 waves,
// 32 KB LDS. Chunk-XOR swizzle via pre-swizzled global source -> 0 conflicts.
// MODE 0: fp32 out.  MODE 1: scatter bf16 q,k->[B,H,T,64] (q pre-scaled),
//                            v -> transposed [B,H,64,T].
template <int MODE>
__global__ __launch_bounds__(256, 4) void gemm_bt(
    const u16* __restrict__ A, const u16* __restrict__ Bt,
    const float* __restrict__ bias, float* __restrict__ outf,
    u16* __restrict__ qo, u16* __restrict__ ko, u16* __restrict__ vo,
    int M, int N, int K) {
  __shared__ u16 As[128 * 64];   // 16 KB, rows 128B, chunk-swizzled
  __shared__ u16 Bs[128 * 64];   // 16 KB

  int nwg = gridDim.x;
  int bid0 = blockIdx.x;
  int bid = (bid0 & 7) * (nwg >> 3) + (bid0 >> 3);   // XCD swizzle (nwg%8==0)
  int nbn = N >> 7;
  int bm = bid / nbn, bn = bid % nbn;
  int m0 = bm * 128, n0 = bn * 128;
  int tid = threadIdx.x;
  int lane = tid & 63, w = tid >> 6;
  int wm = (w >> 1) * 64, wn = (w & 1) * 64;
  int l15 = lane & 15, g = lane >> 4;

  f32x4 acc[4][4] = {};

  for (int kb = 0; kb < K; kb += 64) {
    __syncthreads();  // all waves done reading previous tile
#pragma unroll
    for (int p = 0; p < 4; ++p) {
      int idx = p * 256 + tid;
      int row = idx >> 3, pc = idx & 7;
      int sc = (pc ^ (row & 7)) * 8;     // pre-swizzled source chunk
      gload_lds16(A  + (size_t)(m0 + row) * K + kb + sc, &As[idx * 8]);
      gload_lds16(Bt + (size_t)(n0 + row) * K + kb + sc, &Bs[idx * 8]);
    }
    __syncthreads();  // (compiler emits vmcnt(0) before barrier)

#pragma unroll
    for (int ks = 0; ks < 2; ++ks) {
      int ck = ((g + 4 * ks) ^ (l15 & 7)) * 8;   // swizzled read chunk
      s16x8 af[4], bf[4];
#pragma unroll
      for (int mi = 0; mi < 4; ++mi)
        af[mi] = *(const s16x8*)&As[(wm + mi * 16 + l15) * 64 + ck];
#pragma unroll
      for (int ni = 0; ni < 4; ++ni)
        bf[ni] = *(const s16x8*)&Bs[(wn + ni * 16 + l15) * 64 + ck];
#pragma unroll
      for (int mi = 0; mi < 4; ++mi)
#pragma unroll
        for (int ni = 0; ni < 4; ++ni)
          acc[mi][ni] = __builtin_amdgcn_mfma_f32_16x16x32_bf16(
              af[mi], bf[ni], acc[mi][ni], 0, 0, 0);
    }
  }

#pragma unroll
  for (int mi = 0; mi < 4; ++mi)
#pragma unroll
    for (int ni = 0; ni < 4; ++ni) {
      int col = n0 + wn + ni * 16 + l15;
      float bv = bias[col];
      int row0 = m0 + wm + mi * 16 + g * 4;  // C/D: col=lane&15, row=(lane>>4)*4+reg
      if (MODE == 0) {
#pragma unroll
        for (int r = 0; r < 4; ++r)
          outf[(size_t)(row0 + r) * N + col] = acc[mi][ni][r] + bv;
      } else {
        int which = col >> 10, hc = col & 1023;
        int h = hc >> 6, d = hc & 63;
        int b = row0 >> 11, t0 = row0 & 2047;
        if (which == 2) {
          s16x4 pv;
#pragma unroll
          for (int r = 0; r < 4; ++r) pv[r] = (short)f2b(acc[mi][ni][r] + bv);
          *(s16x4*)(vo + ((size_t)((b * 16 + h) * 64 + d)) * 2048 + t0) = pv;
        } else {
          u16* dst = (which == 0) ? qo : ko;
          float sc2 = (which == 0) ? QSCALE : 1.0f;
#pragma unroll
          for (int r = 0; r < 4; ++r)
            dst[(((size_t)(b * 16 + h)) * 2048 + (t0 + r)) * 64 + d] =
                f2b((acc[mi][ni][r] + bv) * sc2);
        }
      }
    }
}

// ---------------- flash attention, causal, 32x32 MFMA, swapped QK^T ----
// grid: 64 (b,h) x 16 q-tiles of 128 rows; block 256 = 4 waves x 32 q-rows
// (r10 geometry — best measured). K and V^T tiles staged DIRECTLY via
// global_load_lds (both are row-major 128B-row copies; V pre-transposed
// by the QKV GEMM) with pre-swizzled global source -> no ds_writes, no
// staging registers, single barrier per tile (stage t+1 -> compute t ->
// sync drains). S^T = mfma32(K, Q); P in-register via cvt_pk+send-select.
__global__ __launch_bounds__(256, 3) void attn_fwd(
    const u16* __restrict__ Q, const u16* __restrict__ Kg,
    const u16* __restrict__ Vt, u16* __restrict__ Y) {
  __shared__ u16 Ks[2][64 * 64];   // [buf][kv][hd], 8 KB each, swizzled
  __shared__ u16 Vs[2][64 * 64];   // [buf][hd][kv]

  int bid = blockIdx.x;
  int bh = bid & 63;
  int qb = 15 - (bid >> 6);       // big tiles first
  int tid = threadIdx.x, lane = tid & 63, w = tid >> 6;
  int l31 = lane & 31, half = lane >> 5;

  const u16* Qh = Q  + (size_t)bh * T_ * HD_;
  const u16* Kh = Kg + (size_t)bh * T_ * HD_;
  const u16* Vh = Vt + (size_t)bh * HD_ * T_;   // [64][2048]

  int q0 = qb * 128;
  int qw = q0 + w * 32;           // wave's first q row
  int qrow = qw + l31;            // THIS lane's q row

  // Q in registers: 4 k-steps x 16B (k = kst*16 + half*8 + e)
  s16x8 qa[4];
#pragma unroll
  for (int kst = 0; kst < 4; ++kst)
    qa[kst] = *(const s16x8*)(Qh + (size_t)qrow * HD_ + kst * 16 + half * 8);

  f32x16 oacc[2] = {};            // O^T: [hb] -> hd = hb*32+(r&3)+8(r>>2)+4*half
  float m = -3.0e30f, l = 0.f;

  // staging: thread handles rows srow and srow+32 of each tile, chunk tid&7
  int srow = tid >> 3;                       // 0..31
  int sc = ((tid & 7) ^ (srow & 7)) * 8;     // pre-swizzled source chunk (u16)
  int rswz = (l31 & 7) << 4;                 // read-side XOR (bytes)

  // STAGE: 4 gload_lds/thread -> 16 KB (K 8KB + V^T 8KB), linear dest
#define STAGE(bb, kvb_) do { \
  gload_lds16(Kh + (size_t)((kvb_) + srow) * HD_ + sc,      &Ks[bb][tid * 8]); \
  gload_lds16(Kh + (size_t)((kvb_) + 32 + srow) * HD_ + sc, &Ks[bb][(256 + tid) * 8]); \
  gload_lds16(Vh + (size_t)srow * T_ + (kvb_) + sc,         &Vs[bb][tid * 8]); \
  gload_lds16(Vh + (size_t)(32 + srow) * T_ + (kvb_) + sc,  &Vs[bb][(256 + tid) * 8]); \
} while (0)

  int ntile = 2 * qb + 2;
  STAGE(0, 0);
  __syncthreads();                // tile 0 resident (vmcnt drained at barrier)

  for (int kt = 0; kt < ntile; ++kt) {
    int cur = kt & 1;
    int kvb = kt * 64;
    int kvn = (kt + 1 < ntile) ? (kt + 1) * 64 : 0;
    STAGE(cur ^ 1, kvn);          // in flight across the whole compute phase

    if (kvb <= qw + 31) {         // wave-level skip of fully-masked tiles
      char* KsB = (char*)Ks[cur];
      char* VsB = (char*)Vs[cur];

      // S^T = K Q^T per kv-32-block (D: col=q=l31, row=kv=(r&3)+8(r>>2)+4*half)
      f32x16 s0 = {}, s1 = {};
      __builtin_amdgcn_s_setprio(1);
#pragma unroll
      for (int kst = 0; kst < 4; ++kst) {
        s16x8 kb0 = *(const s16x8*)(KsB +
            ((l31 * 128 + kst * 32 + half * 16) ^ rswz));
        s0 = __builtin_amdgcn_mfma_f32_32x32x16_bf16(kb0, qa[kst], s0, 0, 0, 0);
        s16x8 kb1 = *(const s16x8*)(KsB +
            (((32 + l31) * 128 + kst * 32 + half * 16) ^ rswz));
        s1 = __builtin_amdgcn_mfma_f32_32x32x16_bf16(kb1, qa[kst], s1, 0, 0, 0);
      }
      __builtin_amdgcn_s_setprio(0);

      // causal mask (only tiles that can cross the diagonal for this wave)
      if (kvb + 63 > qw) {
#pragma unroll
        for (int r = 0; r < 16; ++r) {
          int kv0 = kvb + (r & 3) + 8 * (r >> 2) + 4 * half;
          if (kv0 > qrow) s0[r] = -1e30f;
          if (kv0 + 32 > qrow) s1[r] = -1e30f;
        }
      }

      // row max: in-lane tree over 32 values + ONE cross-lane combine (^32)
      float a0 = fmaxf(fmaxf(s0[0], s0[1]), fmaxf(s0[2], s0[3]));
      float a1 = fmaxf(fmaxf(s0[4], s0[5]), fmaxf(s0[6], s0[7]));
      float a2 = fmaxf(fmaxf(s0[8], s0[9]), fmaxf(s0[10], s0[11]));
      float a3 = fmaxf(fmaxf(s0[12], s0[13]), fmaxf(s0[14], s0[15]));
      float a4 = fmaxf(fmaxf(s1[0], s1[1]), fmaxf(s1[2], s1[3]));
      float a5 = fmaxf(fmaxf(s1[4], s1[5]), fmaxf(s1[6], s1[7]));
      float a6 = fmaxf(fmaxf(s1[8], s1[9]), fmaxf(s1[10], s1[11]));
      float a7 = fmaxf(fmaxf(s1[12], s1[13]), fmaxf(s1[14], s1[15]));
      float mx = fmaxf(fmaxf(fmaxf(a0, a1), fmaxf(a2, a3)),
                       fmaxf(fmaxf(a4, a5), fmaxf(a6, a7)));
      mx = fmaxf(mx, __shfl_xor(mx, 32, 64));

      // T13 defer-max: skip rescale while max grows < 8 (log2 domain)
      if (!__all(mx <= m + 8.0f)) {
        float mn = fmaxf(m, mx);
        float alpha = __builtin_amdgcn_exp2f(m - mn);
        m = mn;
        l *= alpha;
#pragma unroll
        for (int i = 0; i < 16; ++i) { oacc[0][i] *= alpha; oacc[1][i] *= alpha; }
      }

      float rs = 0.f;
#pragma unroll
      for (int r = 0; r < 16; ++r) {
        float p0 = __builtin_amdgcn_exp2f(s0[r] - m);
        float p1 = __builtin_amdgcn_exp2f(s1[r] - m);
        s0[r] = p0; s1[r] = p1;
        rs += p0 + p1;
      }
      rs += __shfl_xor(rs, 32, 64);
      l += rs;

      // P^T B-fragments (cvt_pk + send-select shfl_xor(32), verified r10)
      s16x8 pb[4];
#pragma unroll
      for (int ks4 = 0; ks4 < 4; ++ks4) {
        const f32x16& sv = (ks4 < 2) ? s0 : s1;
        const int R = (ks4 & 1) * 8;
        uint32_t A0 = cvtpk(sv[R + 0], sv[R + 1]);
        uint32_t A1 = cvtpk(sv[R + 2], sv[R + 3]);
        uint32_t B0 = cvtpk(sv[R + 4], sv[R + 5]);
        uint32_t B1 = cvtpk(sv[R + 6], sv[R + 7]);
        uint32_t r0 = (uint32_t)__shfl_xor((int)(half ? A0 : B0), 32, 64);
        uint32_t r1 = (uint32_t)__shfl_xor((int)(half ? A1 : B1), 32, 64);
        union { uint32_t u[4]; s16x8 v; } pk_;
        pk_.u[0] = half ? r0 : A0;
        pk_.u[1] = half ? r1 : A1;
        pk_.u[2] = half ? B0 : r0;
        pk_.u[3] = half ? B1 : r1;
        pb[ks4] = pk_.v;
      }

      // O^T += V^T P^T: A = V^T fragment (b128), B = pb (in regs)
      __builtin_amdgcn_s_setprio(1);
#pragma unroll
      for (int hb = 0; hb < 2; ++hb)
#pragma unroll
        for (int ks4 = 0; ks4 < 4; ++ks4) {
          s16x8 va = *(const s16x8*)(VsB +
              (((hb * 32 + l31) * 128 + ks4 * 32 + half * 16) ^ rswz));
          oacc[hb] = __builtin_amdgcn_mfma_f32_32x32x16_bf16(va, pb[ks4],
                                                             oacc[hb], 0, 0, 0);
        }
      __builtin_amdgcn_s_setprio(0);
    }

    __syncthreads();   // drains tile t+1 loads; all waves done with buf[cur]
  }
#undef STAGE

  // epilogue: Y[b][q][h*64 + hd], hd = hb*32 + rg*8 + half*4 + i
  int b = bh >> 4, h = bh & 15;
  float inv = 1.0f / l;
  u16* yrow = Y + ((size_t)b * T_ + qrow) * C_ + h * 64;
#pragma unroll
  for (int hb = 0; hb < 2; ++hb)
#pragma unroll
    for (int rg = 0; rg < 4; ++rg) {
      union { uint32_t u[2]; s16x4 v; } o;
      o.u[0] = cvtpk(oacc[hb][rg * 4 + 0] * inv, oacc[hb][rg * 4 + 1] * inv);
      o.u[1] = cvtpk(oacc[hb][rg * 4 + 2] * inv, oacc[hb][rg * 4 + 3] * inv);
      *(s16x4*)(yrow + hb * 32 + rg * 8 + half * 4) = o.v;
    }
}

// ----------------------------- launcher --------------------------------
extern "C" void kernel_launch(void* const* d_in, const int* in_sizes, int n_in,
                              void* d_out, int out_size, void* d_ws, size_t ws_size,
                              hipStream_t stream) {
  const float* x      = (const float*)d_in[0];
  const float* w_attn = (const float*)d_in[1];
  const float* b_attn = (const float*)d_in[2];
  const float* w_proj = (const float*)d_in[3];
  const float* b_proj = (const float*)d_in[4];
  float* out = (float*)d_out;

  u16* ws  = (u16*)d_ws;
  u16* xb  = ws;                           // [8192][1024] bf16 (reused as ya)
  u16* wat = xb  + (size_t)M_ * C_;        // [3072][1024] bf16 (W_attn^T)
  u16* wpt = wat + (size_t)N3_ * C_;       // [1024][1024] bf16 (W_proj^T)
  u16* q   = wpt + (size_t)C_ * C_;        // [B,H,T,64] bf16 (pre-scaled)
  u16* k   = q   + (size_t)M_ * C_;        // [B,H,T,64] bf16
  u16* v   = k   + (size_t)M_ * C_;        // [B,H,64,T] bf16 (TRANSPOSED)
  u16* ya  = xb;                           // reuse: xb dead after QKV GEMM

  cvt_f32_bf16<<<dim3((M_ * C_) / (256 * 8)), dim3(256), 0, stream>>>(x, xb, M_ * C_);
  cvt_transpose<<<dim3(N3_ / 64, C_ / 64), dim3(256), 0, stream>>>(w_attn, wat, C_, N3_);
  cvt_transpose<<<dim3(C_ / 64, C_ / 64), dim3(256), 0, stream>>>(w_proj, wpt, C_, C_);

  gemm_bt<1><<<dim3((M_ / 128) * (N3_ / 128)), dim3(256), 0, stream>>>(
      xb, wat, b_attn, nullptr, q, k, v, M_, N3_, C_);

  attn_fwd<<<dim3(64 * 16), dim3(256), 0, stream>>>(q, k, v, ya);

  gemm_bt<0><<<dim3((M_ / 128) * (C_ / 128)), dim3(256), 0, stream>>>(
      ya, wpt, b_proj, out, nullptr, nullptr, nullptr, M_, C_, C_);
}

// Round 15
// 165.912 us; speedup vs baseline: 1.1114x; 1.0499x over previous
//
#include <hip/hip_runtime.h>
#include <cstdint>

typedef unsigned short u16;
typedef short s16x8 __attribute__((ext_vector_type(8)));
typedef short s16x4 __attribute__((ext_vector_type(4)));
typedef float f32x4 __attribute__((ext_vector_type(4)));
typedef float f32x16 __attribute__((ext_vector_type(16)));

#define B_   4
#define T_   2048
#define C_   1024
#define H_   16
#define HD_  64
#define M_   8192      // B*T
#define N3_  3072      // 3*C

// 0.125 (1/sqrt(64)) * log2(e), folded into q at QKV-GEMM epilogue
#define QSCALE 0.18033688011112042f

// fp32 -> bf16 round-to-nearest-even
__device__ inline u16 f2b(float f) {
  union { float f; uint32_t u; } v; v.f = f;
  uint32_t u = v.u;
  return (u16)((u + 0x7FFFu + ((u >> 16) & 1u)) >> 16);
}

// pack 2 fp32 -> 2 bf16 in one dword (RNE): dst.lo = src0, dst.hi = src1
__device__ inline uint32_t cvtpk(float lo, float hi) {
  uint32_t r;
  asm("v_cvt_pk_bf16_f32 %0, %1, %2" : "=v"(r) : "v"(lo), "v"(hi));
  return r;
}

// async global->LDS, 16B per lane (dest = wave-uniform base + lane*16)
__device__ inline void gload_lds16(const void* g, void* l) {
  __builtin_amdgcn_global_load_lds(
      (const __attribute__((address_space(1))) void*)g,
      (__attribute__((address_space(3))) void*)l, 16, 0, 0);
}

// ------- convert x (fp32) -> bf16, grid-stride (2048 blocks) -----------
__global__ __launch_bounds__(256) void cvt_f32_bf16(
    const float* __restrict__ in, u16* __restrict__ out, int n) {
  int stride = gridDim.x * 256 * 8;
  for (int i = (blockIdx.x * 256 + threadIdx.x) * 8; i < n; i += stride) {
    float4 a = *(const float4*)(in + i);
    float4 b = *(const float4*)(in + i + 4);
    s16x8 r;
    r[0] = (short)f2b(a.x); r[1] = (short)f2b(a.y);
    r[2] = (short)f2b(a.z); r[3] = (short)f2b(a.w);
    r[4] = (short)f2b(b.x); r[5] = (short)f2b(b.y);
    r[6] = (short)f2b(b.z); r[7] = (short)f2b(b.w);
    *(s16x8*)(out + i) = r;
  }
}

// ------- transpose+convert: W fp32 [K][N] -> WT bf16 [N][K] ------------
__global__ __launch_bounds__(256) void cvt_transpose(
    const float* __restrict__ W, u16* __restrict__ WT, int K, int N) {
  __shared__ u16 tile[64][65];
  int n0 = blockIdx.x * 64, k0 = blockIdx.y * 64;
  int j = threadIdx.x & 63, i0 = threadIdx.x >> 6;  // j fast, i0 in 0..3
#pragma unroll
  for (int i = i0; i < 64; i += 4)
    tile[i][j] = f2b(W[(size_t)(k0 + i) * N + n0 + j]);
  __syncthreads();
#pragma unroll
  for (int i = i0; i < 64; i += 4)
    WT[(size_t)(n0 + i) * K + k0 + j] = tile[j][i];
}

// ---------------- GEMM: C[M][N] = A[M][K] * Bt[N][K]^T + bias ----------
// 2-barrier structure (measured-best), BK=64, 128x128 tile, 4 waves,
// 32 KB LDS. Chunk-XOR swizzle via pre-swizzled global source -> 0 conflicts.
// MODE 0: fp32 out.  MODE 1: scatter bf16 q,k->[B,H,T,64] (q pre-scaled),
//                            v -> transposed [B,H,64,T].
template <int MODE>
__global__ __launch_bounds__(256, 4) void gemm_bt(
    const u16* __restrict__ A, const u16* __restrict__ Bt,
    const float* __restrict__ bias, float* __restrict__ outf,
    u16* __restrict__ qo, u16* __restrict__ ko, u16* __restrict__ vo,
    int M, int N, int K) {
  __shared__ u16 As[128 * 64];   // 16 KB, rows 128B, chunk-swizzled
  __shared__ u16 Bs[128 * 64];   // 16 KB

  int nwg = gridDim.x;
  int bid0 = blockIdx.x;
  int bid = (bid0 & 7) * (nwg >> 3) + (bid0 >> 3);   // XCD swizzle (nwg%8==0)
  int nbn = N >> 7;
  int bm = bid / nbn, bn = bid % nbn;
  int m0 = bm * 128, n0 = bn * 128;
  int tid = threadIdx.x;
  int lane = tid & 63, w = tid >> 6;
  int wm = (w >> 1) * 64, wn = (w & 1) * 64;
  int l15 = lane & 15, g = lane >> 4;

  f32x4 acc[4][4] = {};

  for (int kb = 0; kb < K; kb += 64) {
    __syncthreads();  // all waves done reading previous tile
#pragma unroll
    for (int p = 0; p < 4; ++p) {
      int idx = p * 256 + tid;
      int row = idx >> 3, pc = idx & 7;
      int sc = (pc ^ (row & 7)) * 8;     // pre-swizzled source chunk
      gload_lds16(A  + (size_t)(m0 + row) * K + kb + sc, &As[idx * 8]);
      gload_lds16(Bt + (size_t)(n0 + row) * K + kb + sc, &Bs[idx * 8]);
    }
    __syncthreads();  // (compiler emits vmcnt(0) before barrier)

#pragma unroll
    for (int ks = 0; ks < 2; ++ks) {
      int ck = ((g + 4 * ks) ^ (l15 & 7)) * 8;   // swizzled read chunk
      s16x8 af[4], bf[4];
#pragma unroll
      for (int mi = 0; mi < 4; ++mi)
        af[mi] = *(const s16x8*)&As[(wm + mi * 16 + l15) * 64 + ck];
#pragma unroll
      for (int ni = 0; ni < 4; ++ni)
        bf[ni] = *(const s16x8*)&Bs[(wn + ni * 16 + l15) * 64 + ck];
#pragma unroll
      for (int mi = 0; mi < 4; ++mi)
#pragma unroll
        for (int ni = 0; ni < 4; ++ni)
          acc[mi][ni] = __builtin_amdgcn_mfma_f32_16x16x32_bf16(
              af[mi], bf[ni], acc[mi][ni], 0, 0, 0);
    }
  }

#pragma unroll
  for (int mi = 0; mi < 4; ++mi)
#pragma unroll
    for (int ni = 0; ni < 4; ++ni) {
      int col = n0 + wn + ni * 16 + l15;
      float bv = bias[col];
      int row0 = m0 + wm + mi * 16 + g * 4;  // C/D: col=lane&15, row=(lane>>4)*4+reg
      if (MODE == 0) {
#pragma unroll
        for (int r = 0; r < 4; ++r)
          outf[(size_t)(row0 + r) * N + col] = acc[mi][ni][r] + bv;
      } else {
        int which = col >> 10, hc = col & 1023;
        int h = hc >> 6, d = hc & 63;
        int b = row0 >> 11, t0 = row0 & 2047;
        if (which == 2) {
          s16x4 pv;
#pragma unroll
          for (int r = 0; r < 4; ++r) pv[r] = (short)f2b(acc[mi][ni][r] + bv);
          *(s16x4*)(vo + ((size_t)((b * 16 + h) * 64 + d)) * 2048 + t0) = pv;
        } else {
          u16* dst = (which == 0) ? qo : ko;
          float sc2 = (which == 0) ? QSCALE : 1.0f;
#pragma unroll
          for (int r = 0; r < 4; ++r)
            dst[(((size_t)(b * 16 + h)) * 2048 + (t0 + r)) * 64 + d] =
                f2b((acc[mi][ni][r] + bv) * sc2);
        }
      }
    }
}

// ---------------- flash attention, causal, 32x32 MFMA, swapped QK^T ----
// (r10 verbatim — best measured: ~59 us, occupancy ~36%)
// grid: 64 (b,h) x 16 q-tiles of 128 rows; block 256 = 4 waves x 32 q-rows
// S^T = mfma32(K, Q): lane holds one q-row (q=lane&31), 32 kv vals in regs.
// PV as O^T = V^T * P^T via 32x32x16: P stays in-register; B-fragment
// redistribution via cvt_pk + send-select shfl_xor(32) + cndmask.
__global__ __launch_bounds__(256, 3) void attn_fwd(
    const u16* __restrict__ Q, const u16* __restrict__ Kg,
    const u16* __restrict__ Vt, u16* __restrict__ Y) {
  __shared__ u16 Ks[64 * 64];   // K tile  [kv][hd], 128B rows, swizzled
  __shared__ u16 Vs[64 * 64];   // V^T tile [hd][kv], 128B rows, swizzled

  int bid = blockIdx.x;
  int bh = bid & 63;
  int qb = 15 - (bid >> 6);       // big tiles first
  int tid = threadIdx.x, lane = tid & 63, w = tid >> 6;
  int l31 = lane & 31, half = lane >> 5;

  const u16* Qh = Q  + (size_t)bh * T_ * HD_;
  const u16* Kh = Kg + (size_t)bh * T_ * HD_;
  const u16* Vh = Vt + (size_t)bh * HD_ * T_;   // [64][2048]

  int q0 = qb * 128;
  int qw = q0 + w * 32;           // wave's first q row
  int qrow = qw + l31;            // THIS lane's q row

  // Q in registers: 4 k-steps x 16B (k = kst*16 + half*8 + e)
  s16x8 qa[4];
#pragma unroll
  for (int kst = 0; kst < 4; ++kst)
    qa[kst] = *(const s16x8*)(Qh + (size_t)qrow * HD_ + kst * 16 + half * 8);

  f32x16 oacc[2] = {};            // O^T: [hb] -> hd = hb*32+(r&3)+8(r>>2)+4*half
  float m = -3.0e30f, l = 0.f;

  // staging: thread stages rows sr and sr+32, 16B chunk sc
  int sr = tid >> 3, sc = tid & 7;
  int wswz = (sr & 7) << 4;       // write-side swizzle (same for sr+32)
  int rswz = (l31 & 7) << 4;      // read-side swizzle (rows = base + l31)
  char* KsB = (char*)Ks;
  char* VsB = (char*)Vs;

  // preload tile 0 into registers
  s16x8 kr0 = *(const s16x8*)(Kh + (size_t)sr * HD_ + sc * 8);
  s16x8 kr1 = *(const s16x8*)(Kh + (size_t)(sr + 32) * HD_ + sc * 8);
  s16x8 vr0 = *(const s16x8*)(Vh + (size_t)sr * T_ + sc * 8);
  s16x8 vr1 = *(const s16x8*)(Vh + (size_t)(sr + 32) * T_ + sc * 8);

  int ntile = 2 * qb + 2;
  for (int kt = 0; kt < ntile; ++kt) {
    int kvb = kt * 64;
    __syncthreads();              // previous tile's reads done
    *(s16x8*)(KsB + sr * 128 + ((sc * 16) ^ wswz))        = kr0;
    *(s16x8*)(KsB + (sr + 32) * 128 + ((sc * 16) ^ wswz)) = kr1;
    *(s16x8*)(VsB + sr * 128 + ((sc * 16) ^ wswz))        = vr0;
    *(s16x8*)(VsB + (sr + 32) * 128 + ((sc * 16) ^ wswz)) = vr1;
    __syncthreads();              // tile visible

    // T14: issue NEXT tile's global loads now; latency hides under compute
    {
      int kvn = (kt + 1 < ntile) ? (kt + 1) * 64 : 0;
      kr0 = *(const s16x8*)(Kh + (size_t)(kvn + sr) * HD_ + sc * 8);
      kr1 = *(const s16x8*)(Kh + (size_t)(kvn + sr + 32) * HD_ + sc * 8);
      vr0 = *(const s16x8*)(Vh + (size_t)sr * T_ + kvn + sc * 8);
      vr1 = *(const s16x8*)(Vh + (size_t)(sr + 32) * T_ + kvn + sc * 8);
    }

    // wave-level skip of fully-masked tiles (barriers stay block-uniform)
    if (kvb > qw + 31) continue;

    // S^T = K Q^T per kv-32-block (D: col=q=l31, row=kv=(r&3)+8(r>>2)+4*half)
    f32x16 s0 = {}, s1 = {};
    __builtin_amdgcn_s_setprio(1);
#pragma unroll
    for (int kst = 0; kst < 4; ++kst) {
      s16x8 kb0 = *(const s16x8*)(KsB +
          (((l31) * 128 + kst * 32 + half * 16) ^ rswz));
      s0 = __builtin_amdgcn_mfma_f32_32x32x16_bf16(kb0, qa[kst], s0, 0, 0, 0);
      s16x8 kb1 = *(const s16x8*)(KsB +
          (((32 + l31) * 128 + kst * 32 + half * 16) ^ rswz));
      s1 = __builtin_amdgcn_mfma_f32_32x32x16_bf16(kb1, qa[kst], s1, 0, 0, 0);
    }
    __builtin_amdgcn_s_setprio(0);

    // causal mask (only tiles that can cross the diagonal for this wave)
    if (kvb + 63 > qw) {
#pragma unroll
      for (int r = 0; r < 16; ++r) {
        int kv0 = kvb + (r & 3) + 8 * (r >> 2) + 4 * half;
        if (kv0 > qrow) s0[r] = -1e30f;
        if (kv0 + 32 > qrow) s1[r] = -1e30f;
      }
    }

    // row max: in-lane tree over 32 values + ONE cross-lane combine (^32)
    float a0 = fmaxf(fmaxf(s0[0], s0[1]), fmaxf(s0[2], s0[3]));
    float a1 = fmaxf(fmaxf(s0[4], s0[5]), fmaxf(s0[6], s0[7]));
    float a2 = fmaxf(fmaxf(s0[8], s0[9]), fmaxf(s0[10], s0[11]));
    float a3 = fmaxf(fmaxf(s0[12], s0[13]), fmaxf(s0[14], s0[15]));
    float a4 = fmaxf(fmaxf(s1[0], s1[1]), fmaxf(s1[2], s1[3]));
    float a5 = fmaxf(fmaxf(s1[4], s1[5]), fmaxf(s1[6], s1[7]));
    float a6 = fmaxf(fmaxf(s1[8], s1[9]), fmaxf(s1[10], s1[11]));
    float a7 = fmaxf(fmaxf(s1[12], s1[13]), fmaxf(s1[14], s1[15]));
    float mx = fmaxf(fmaxf(fmaxf(a0, a1), fmaxf(a2, a3)),
                     fmaxf(fmaxf(a4, a5), fmaxf(a6, a7)));
    mx = fmaxf(mx, __shfl_xor(mx, 32, 64));

    // T13 defer-max: skip rescale while max grows < 8 (log2 domain)
    if (!__all(mx <= m + 8.0f)) {
      float mn = fmaxf(m, mx);
      float alpha = __builtin_amdgcn_exp2f(m - mn);
      m = mn;
      l *= alpha;
#pragma unroll
      for (int i = 0; i < 16; ++i) { oacc[0][i] *= alpha; oacc[1][i] *= alpha; }
    }

    float rs = 0.f;
#pragma unroll
    for (int r = 0; r < 16; ++r) {
      float p0 = __builtin_amdgcn_exp2f(s0[r] - m);
      float p1 = __builtin_amdgcn_exp2f(s1[r] - m);
      s0[r] = p0; s1[r] = p1;
      rs += p0 + p1;
    }
    rs += __shfl_xor(rs, 32, 64);
    l += rs;

    // P^T B-fragments: lane (l31,half) needs kv = ks4*16 + half*8 + {0..7}.
    // Send-select: shfl(half?A:B) delivers exactly the partner dwords.
    s16x8 pb[4];
#pragma unroll
    for (int ks4 = 0; ks4 < 4; ++ks4) {
      const f32x16& sv = (ks4 < 2) ? s0 : s1;
      const int R = (ks4 & 1) * 8;
      uint32_t A0 = cvtpk(sv[R + 0], sv[R + 1]);
      uint32_t A1 = cvtpk(sv[R + 2], sv[R + 3]);
      uint32_t B0 = cvtpk(sv[R + 4], sv[R + 5]);
      uint32_t B1 = cvtpk(sv[R + 6], sv[R + 7]);
      uint32_t r0 = (uint32_t)__shfl_xor((int)(half ? A0 : B0), 32, 64);
      uint32_t r1 = (uint32_t)__shfl_xor((int)(half ? A1 : B1), 32, 64);
      union { uint32_t u[4]; s16x8 v; } pk_;
      pk_.u[0] = half ? r0 : A0;   // kv_off 0,1   | 8,9
      pk_.u[1] = half ? r1 : A1;   // kv_off 2,3   | 10,11
      pk_.u[2] = half ? B0 : r0;   // kv_off 4,5   | 12,13
      pk_.u[3] = half ? B1 : r1;   // kv_off 6,7   | 14,15
      pb[ks4] = pk_.v;
    }

    // O^T += V^T P^T: A = V^T fragment (b128), B = pb (in regs)
    __builtin_amdgcn_s_setprio(1);
#pragma unroll
    for (int hb = 0; hb < 2; ++hb)
#pragma unroll
      for (int ks4 = 0; ks4 < 4; ++ks4) {
        s16x8 va = *(const s16x8*)(VsB +
            (((hb * 32 + l31) * 128 + ks4 * 32 + half * 16) ^ rswz));
        oacc[hb] = __builtin_amdgcn_mfma_f32_32x32x16_bf16(va, pb[ks4],
                                                           oacc[hb], 0, 0, 0);
      }
    __builtin_amdgcn_s_setprio(0);
  }

  // epilogue: Y[b][q][h*64 + hd], hd = hb*32 + rg*8 + half*4 + i
  int b = bh >> 4, h = bh & 15;
  float inv = 1.0f / l;
  u16* yrow = Y + ((size_t)b * T_ + qrow) * C_ + h * 64;
#pragma unroll
  for (int hb = 0; hb < 2; ++hb)
#pragma unroll
    for (int rg = 0; rg < 4; ++rg) {
      union { uint32_t u[2]; s16x4 v; } o;
      o.u[0] = cvtpk(oacc[hb][rg * 4 + 0] * inv, oacc[hb][rg * 4 + 1] * inv);
      o.u[1] = cvtpk(oacc[hb][rg * 4 + 2] * inv, oacc[hb][rg * 4 + 3] * inv);
      *(s16x4*)(yrow + hb * 32 + rg * 8 + half * 4) = o.v;
    }
}

// ----------------------------- launcher --------------------------------
extern "C" void kernel_launch(void* const* d_in, const int* in_sizes, int n_in,
                              void* d_out, int out_size, void* d_ws, size_t ws_size,
                              hipStream_t stream) {
  const float* x      = (const float*)d_in[0];
  const float* w_attn = (const float*)d_in[1];
  const float* b_attn = (const float*)d_in[2];
  const float* w_proj = (const float*)d_in[3];
  const float* b_proj = (const float*)d_in[4];
  float* out = (float*)d_out;

  u16* ws  = (u16*)d_ws;
  u16* xb  = ws;                           // [8192][1024] bf16 (reused as ya)
  u16* wat = xb  + (size_t)M_ * C_;        // [3072][1024] bf16 (W_attn^T)
  u16* wpt = wat + (size_t)N3_ * C_;        // [1024][1024] bf16 (W_proj^T)
  u16* q   = wpt + (size_t)C_ * C_;        // [B,H,T,64] bf16 (pre-scaled)
  u16* k   = q   + (size_t)M_ * C_;        // [B,H,T,64] bf16
  u16* v   = k   + (size_t)M_ * C_;        // [B,H,64,T] bf16 (TRANSPOSED)
  u16* ya  = xb;                           // reuse: xb dead after QKV GEMM

  cvt_f32_bf16<<<dim3(2048), dim3(256), 0, stream>>>(x, xb, M_ * C_);
  cvt_transpose<<<dim3(N3_ / 64, C_ / 64), dim3(256), 0, stream>>>(w_attn, wat, C_, N3_);
  cvt_transpose<<<dim3(C_ / 64, C_ / 64), dim3(256), 0, stream>>>(w_proj, wpt, C_, C_);

  gemm_bt<1><<<dim3((M_ / 128) * (N3_ / 128)), dim3(256), 0, stream>>>(
      xb, wat, b_attn, nullptr, q, k, v, M_, N3_, C_);

  attn_fwd<<<dim3(64 * 16), dim3(256), 0, stream>>>(q, k, v, ya);

  gemm_bt<0><<<dim3((M_ / 128) * (C_ / 128)), dim3(256), 0, stream>>>(
      ya, wpt, b_proj, out, nullptr, nullptr, nullptr, M_, C_, C_);
}